// Round 1
// baseline (384.583 us; speedup 1.0000x reference)
//
#include <hip/hip_runtime.h>
#include <math.h>

// Shapes (fixed by setup_inputs): q(8,256,128,128) c_t(8,256,512)
// W_a(512,256) W_p(256,512) V_p(2,256). Out (8,256,256) fp32.
#define Bq 8
#define Tt 256
#define Dd 256
#define Hh 128
#define Ww 128
#define Cc 512
#define HW (Hh*Ww)
#define NBT (Bq*Tt)   // 2048 tokens

// ---------------- Kernel 1: per-token u = c_t@W_a and p_t -----------------
// One block handles TOK tokens; weights stream through L1/L2 once per block.
#define TOK 8
__global__ __launch_bounds__(256) void prep_kernel(
    const float* __restrict__ c_t,   // (NBT, 512)
    const float* __restrict__ W_a,   // (512, 256) row-major
    const float* __restrict__ W_p,   // (256, 512) row-major
    const float* __restrict__ V_p,   // (2, 256)
    float* __restrict__ u_ws,        // (NBT, 256)
    float* __restrict__ p_ws)        // (NBT, 2)
{
    __shared__ float ct[TOK][Cc];    // 16 KB
    __shared__ float red[512];       // 2 KB
    const int tid = threadIdx.x;
    const int bt0 = blockIdx.x * TOK;

    // coalesced float4 load of the c_t tile
    const float4* src = (const float4*)(c_t + (size_t)bt0 * Cc);
    float4* dst = (float4*)&ct[0][0];
    for (int i = tid; i < TOK * Cc / 4; i += 256) dst[i] = src[i];
    __syncthreads();

    float accU[TOK], accH[TOK];
#pragma unroll
    for (int t = 0; t < TOK; t++) { accU[t] = 0.f; accH[t] = 0.f; }

    const float* wa = W_a + tid;                 // W_a[c*256 + tid] : coalesced
    const float* wp = W_p + (size_t)tid * Cc;    // W_p[tid*512 + c] : per-thread stream (L1)
    for (int c = 0; c < Cc; c++) {
        float a = wa[(size_t)c * Dd];
        float p = wp[c];
#pragma unroll
        for (int t = 0; t < TOK; t++) {
            float cv = ct[t][c];                 // LDS broadcast
            accU[t] = fmaf(cv, a, accU[t]);
            accH[t] = fmaf(cv, p, accH[t]);
        }
    }

    // store u (coalesced)
#pragma unroll
    for (int t = 0; t < TOK; t++)
        u_ws[(size_t)(bt0 + t) * Dd + tid] = accU[t];

    // p_t = 128*sigmoid(tanh(h) @ V_p^T), block reduction per token
    const float vp0 = V_p[tid];
    const float vp1 = V_p[256 + tid];
    for (int t = 0; t < TOK; t++) {
        float th = tanhf(accH[t]);
        red[tid]       = th * vp0;
        red[256 + tid] = th * vp1;
        __syncthreads();
        for (int s = 128; s >= 1; s >>= 1) {
            if (tid < s) {
                red[tid]       += red[tid + s];
                red[256 + tid] += red[256 + tid + s];
            }
            __syncthreads();
        }
        if (tid == 0) {
            p_ws[(size_t)(bt0 + t) * 2 + 0] = 128.f / (1.f + expf(-red[0]));
            p_ws[(size_t)(bt0 + t) * 2 + 1] = 128.f / (1.f + expf(-red[256]));
        }
        __syncthreads();
    }
}

// ---------------- Kernel 2: gather + scores + softmax + output ------------
// One block per token.
__global__ __launch_bounds__(256) void attn_kernel(
    const float* __restrict__ q,     // (8,256,128,128)
    const float* __restrict__ u_ws,  // (NBT,256)
    const float* __restrict__ p_ws,  // (NBT,2)
    float* __restrict__ out)         // (NBT,256)
{
    __shared__ float u_s[Dd];
    __shared__ float a_red[243];
    __shared__ int   off_s[81];      // -1 encodes NaN-pad (invalid) position
    __shared__ float w_s[81];
    __shared__ float a_s[81];
    __shared__ float e_s[81];
    __shared__ float rex_s[9], cex_s[9];
    __shared__ int   rr_s[9], cc_s[9];
    __shared__ float m_sh, inv_sh;

    const int tid = threadIdx.x;
    const int bt  = blockIdx.x;
    const int b   = bt >> 8;         // T = 256

    u_s[tid] = u_ws[(size_t)bt * Dd + tid];

    // window indices + gaussian exponents (threads 0..17)
    if (tid < 18) {
        int  i = (tid < 9) ? tid : tid - 9;
        float p = p_ws[(size_t)bt * 2 + ((tid < 9) ? 0 : 1)];
        int base = (int)rintf(p);                 // round-half-even, matches jnp.round
        int v = base + i - 3;                     // round(p)+off+1, off=i-4
        v = min(max(v, 0), 129) % 129;            // clip to [0,129] then mod 129
        float cl = (float)max(v - 1, 0);
        float z  = (cl - p) * 0.25f;              // / (R//2)
        float ex = -2.f * z * z;
        if (tid < 9) { rr_s[i] = v; rex_s[i] = ex; }
        else         { cc_s[i] = v; cex_s[i] = ex; }
    }
    __syncthreads();

    if (tid < 81) {
        int i = (tid * 57) >> 9;                  // k/9 for k<81
        int j = tid - i * 9;
        int r = rr_s[i], c = cc_s[j];
        bool valid = (r > 0) && (c > 0);          // row/col 0 are the NaN pads
        off_s[tid] = valid ? ((r - 1) * Ww + (c - 1)) : -1;
    }
    __syncthreads();

    // ---- pass 1: scores a_k = sum_d qg[k,d]*u[d], thread=(k, s=d%3) ----
    if (tid < 243) {
        int k = tid % 81;
        int s = tid / 81;
        int o = max(off_s[k], 0);
        const float* qp = q + ((size_t)(b * Dd + s)) * HW + o;
        int iters = (s == 0) ? 86 : 85;           // d = s, s+3, ..., < 256
        float ap = 0.f;
        int d = s;
        for (int it = 0; it < iters; it++) {
            ap = fmaf(qp[0], u_s[d], ap);
            qp += 3 * HW;
            d  += 3;
        }
        a_red[tid] = ap;
    }
    __syncthreads();

    float a_val = -INFINITY;
    bool  valid_k = false;
    if (tid < 81) {
        valid_k = (off_s[tid] >= 0);
        float a = a_red[tid] + a_red[tid + 81] + a_red[tid + 162];
        a_val = valid_k ? a : -INFINITY;
        a_s[tid] = a_val;
    }
    __syncthreads();

    // ---- softmax over 81 (wave-0 butterfly) ----
    if (tid < 64) {
        float m = a_s[tid];
        if (tid + 64 < 81) m = fmaxf(m, a_s[tid + 64]);
        for (int o = 32; o >= 1; o >>= 1) m = fmaxf(m, __shfl_xor(m, o));
        if (tid == 0) m_sh = m;
    }
    __syncthreads();
    {
        float e = 0.f;
        if (tid < 81 && valid_k) e = expf(a_val - m_sh);
        if (tid < 81) e_s[tid] = e;
    }
    __syncthreads();
    if (tid < 64) {
        float sv = e_s[tid] + ((tid + 64 < 81) ? e_s[tid + 64] : 0.f);
        for (int o = 32; o >= 1; o >>= 1) sv += __shfl_xor(sv, o);
        if (tid == 0) inv_sh = 1.f / sv;
    }
    __syncthreads();
    if (tid < 81) {
        int i = (tid * 57) >> 9;
        int j = tid - i * 9;
        float g = expf(rex_s[i] + cex_s[j]);      // gaussian applied after softmax
        w_s[tid] = e_s[tid] * inv_sh * g;
    }
    __syncthreads();

    // ---- pass 2: out[d] = sum_k w_k * qg[k,d]; reads are L1/L2-warm ----
    const float* qp = q + ((size_t)(b * Dd + tid)) * HW;
    float acc = 0.f;
    for (int k = 0; k < 81; k++) {
        int o = max(off_s[k], 0);                 // invalid -> safe read, w=0
        acc = fmaf(w_s[k], qp[o], acc);
    }
    out[(size_t)bt * Dd + tid] = acc;
}

extern "C" void kernel_launch(void* const* d_in, const int* in_sizes, int n_in,
                              void* d_out, int out_size, void* d_ws, size_t ws_size,
                              hipStream_t stream) {
    const float* q   = (const float*)d_in[0];
    const float* c_t = (const float*)d_in[1];
    const float* W_a = (const float*)d_in[2];
    const float* W_p = (const float*)d_in[3];
    const float* V_p = (const float*)d_in[4];
    float* out  = (float*)d_out;
    float* u_ws = (float*)d_ws;                   // 2048*256 floats = 2 MB
    float* p_ws = u_ws + (size_t)NBT * Dd;        // 2048*2 floats

    prep_kernel<<<NBT / TOK, 256, 0, stream>>>(c_t, W_a, W_p, V_p, u_ws, p_ws);
    attn_kernel<<<NBT, 256, 0, stream>>>(q, u_ws, p_ws, out);
}

// Round 2
// 290.394 us; speedup vs baseline: 1.3243x; 1.3243x over previous
//
#include <hip/hip_runtime.h>
#include <hip/hip_bf16.h>
#include <math.h>

// Shapes (fixed): q(8,256,128,128) c_t(8,256,512) W_a(512,256) W_p(256,512) V_p(2,256)
#define Bq 8
#define Tt 256
#define Dd 256
#define Hh 128
#define Ww 128
#define Cc 512
#define HW (Hh*Ww)
#define NBT (Bq*Tt)   // 2048 tokens

// ---------------- Kernel 0: transpose W_p (256x512) -> WpT (512x256) ------
__global__ __launch_bounds__(256) void transpose_wp(
    const float* __restrict__ W_p, float* __restrict__ WpT)
{
    __shared__ float tile[32][33];
    const int bx = blockIdx.x;            // c tile (16)
    const int by = blockIdx.y;            // p tile (8)
    const int lx = threadIdx.x & 31, ly = threadIdx.x >> 5;   // 32 x 8
#pragma unroll
    for (int j = 0; j < 4; j++) {
        int p = by * 32 + ly + j * 8;
        tile[ly + j * 8][lx] = W_p[(size_t)p * Cc + bx * 32 + lx];
    }
    __syncthreads();
#pragma unroll
    for (int j = 0; j < 4; j++) {
        int c = bx * 32 + ly + j * 8;
        WpT[(size_t)c * 256 + by * 32 + lx] = tile[lx][ly + j * 8];
    }
}

// ---------------- Kernel 1: u = c_t@W_a, p_t = 128*sig(V_p tanh(W_p c)) ---
// 512 threads: tid<256 -> u columns, tid>=256 -> h columns (via WpT).
// c_t read via wave-uniform addresses -> scalar loads.
#define TOK 8
__global__ __launch_bounds__(512) void prep_kernel(
    const float* __restrict__ c_t,   // (NBT, 512)
    const float* __restrict__ W_a,   // (512, 256)  [c][d]
    const float* __restrict__ WpT,   // (512, 256)  [c][p]
    const float* __restrict__ V_p,   // (2, 256)
    float* __restrict__ u_ws,        // (NBT, 256)
    float* __restrict__ p_ws)        // (NBT, 2)
{
    __shared__ float y0s[TOK][256];
    __shared__ float y1s[TOK][256];
    const int tid  = threadIdx.x;
    const int o    = tid & 255;
    const int half = tid >> 8;
    const int bt0  = blockIdx.x * TOK;

    const float* Wcol = (half ? WpT : W_a) + o;   // column o, stride 256
    const float* ct0  = c_t + (size_t)bt0 * Cc;

    float acc[TOK];
#pragma unroll
    for (int t = 0; t < TOK; t++) acc[t] = 0.f;

    for (int c = 0; c < Cc; c += 4) {
        float w0 = Wcol[(size_t)(c + 0) * 256];
        float w1 = Wcol[(size_t)(c + 1) * 256];
        float w2 = Wcol[(size_t)(c + 2) * 256];
        float w3 = Wcol[(size_t)(c + 3) * 256];
#pragma unroll
        for (int t = 0; t < TOK; t++) {
            const float* r = ct0 + t * Cc + c;    // uniform address -> s_load
            float c0 = r[0], c1 = r[1], c2 = r[2], c3 = r[3];
            acc[t] = fmaf(c0, w0, acc[t]);
            acc[t] = fmaf(c1, w1, acc[t]);
            acc[t] = fmaf(c2, w2, acc[t]);
            acc[t] = fmaf(c3, w3, acc[t]);
        }
    }

    if (half == 0) {
#pragma unroll
        for (int t = 0; t < TOK; t++)
            u_ws[(size_t)(bt0 + t) * Dd + o] = acc[t];
    } else {
        float v0 = V_p[o], v1 = V_p[256 + o];
#pragma unroll
        for (int t = 0; t < TOK; t++) {
            float th = tanhf(acc[t]);
            y0s[t][o] = th * v0;
            y1s[t][o] = th * v1;
        }
    }
    __syncthreads();

    // wave w reduces token w (8 waves == 8 tokens)
    const int wv = tid >> 6, ln = tid & 63;
    float s0 = y0s[wv][ln] + y0s[wv][ln + 64] + y0s[wv][ln + 128] + y0s[wv][ln + 192];
    float s1 = y1s[wv][ln] + y1s[wv][ln + 64] + y1s[wv][ln + 128] + y1s[wv][ln + 192];
#pragma unroll
    for (int of = 32; of >= 1; of >>= 1) {
        s0 += __shfl_xor(s0, of);
        s1 += __shfl_xor(s1, of);
    }
    if (ln == 0) {
        p_ws[(size_t)(bt0 + wv) * 2 + 0] = 128.f / (1.f + expf(-s0));
        p_ws[(size_t)(bt0 + wv) * 2 + 1] = 128.f / (1.f + expf(-s1));
    }
}

// ---------------- Kernel 2: gather + scores + softmax + output ------------
// One block per token. Pass 1: 243 lanes, 5-deep load pipelining, stashes
// the gathered window to LDS (bf16). Pass 2 reads LDS only.
__global__ __launch_bounds__(256) void attn_kernel(
    const float* __restrict__ q,     // (8,256,128,128)
    const float* __restrict__ u_ws,  // (NBT,256)
    const float* __restrict__ p_ws,  // (NBT,2)
    float* __restrict__ out)         // (NBT,256)
{
    __shared__ __hip_bfloat16 win[81][258];   // 41796 B, padded: conflict-free
    __shared__ float u_s[Dd];
    __shared__ float a_red[243];
    __shared__ int   off_s[81];
    __shared__ float w_s[81];
    __shared__ float a_s[81];
    __shared__ float e_s[81];
    __shared__ float rex_s[9], cex_s[9];
    __shared__ int   rr_s[9], cc_s[9];
    __shared__ float m_sh, inv_sh;

    const int tid = threadIdx.x;
    int bt = blockIdx.x;
    bt = ((bt & 7) << 8) | (bt >> 3);    // same-batch tokens -> same XCD
    const int b = bt >> 8;

    u_s[tid] = u_ws[(size_t)bt * Dd + tid];

    if (tid < 18) {
        int   i = (tid < 9) ? tid : tid - 9;
        float p = p_ws[(size_t)bt * 2 + ((tid < 9) ? 0 : 1)];
        int base = (int)rintf(p);                 // round-half-even = jnp.round
        int v = base + i - 3;                     // round(p)+off+1, off=i-4
        v = min(max(v, 0), 129) % 129;
        float cl = (float)max(v - 1, 0);
        float z  = (cl - p) * 0.25f;
        float ex = -2.f * z * z;
        if (tid < 9) { rr_s[i] = v; rex_s[i] = ex; }
        else         { cc_s[i] = v; cex_s[i] = ex; }
    }
    __syncthreads();

    if (tid < 81) {
        int i = (tid * 57) >> 9;                  // tid/9
        int j = tid - i * 9;
        int r = rr_s[i], c = cc_s[j];
        bool valid = (r > 0) && (c > 0);
        off_s[tid] = valid ? ((r - 1) * Ww + (c - 1)) : -1;
    }
    __syncthreads();

    // ---- pass 1: a_k = sum_d qg[k,d]*u[d]; lane=(k, s=d%3), 5-deep MLP ----
    if (tid < 243) {
        const int k = tid % 81;
        const int s = tid / 81;
        const int o = max(off_s[k], 0);
        const float* qp = q + ((size_t)(b * Dd + s)) * HW + o;
        const size_t st = (size_t)3 * HW;
        float ap = 0.f;
        int d = s;
        if (s == 0) {                              // peel d=0 so all lanes do 85
            float x = qp[0];
            win[k][0] = __float2bfloat16(x);
            ap = fmaf(x, u_s[0], ap);
            qp += st; d = 3;
        }
        for (int it = 0; it < 17; it++) {          // 17 x 5 = 85
            float x0 = qp[0];
            float x1 = qp[st];
            float x2 = qp[2 * st];
            float x3 = qp[3 * st];
            float x4 = qp[4 * st];
            win[k][d     ] = __float2bfloat16(x0);
            win[k][d + 3 ] = __float2bfloat16(x1);
            win[k][d + 6 ] = __float2bfloat16(x2);
            win[k][d + 9 ] = __float2bfloat16(x3);
            win[k][d + 12] = __float2bfloat16(x4);
            ap = fmaf(x0, u_s[d     ], ap);
            ap = fmaf(x1, u_s[d + 3 ], ap);
            ap = fmaf(x2, u_s[d + 6 ], ap);
            ap = fmaf(x3, u_s[d + 9 ], ap);
            ap = fmaf(x4, u_s[d + 12], ap);
            qp += 5 * st;
            d  += 15;
        }
        a_red[tid] = ap;
    }
    __syncthreads();

    float a_val = -INFINITY;
    bool  valid_k = false;
    if (tid < 81) {
        valid_k = (off_s[tid] >= 0);
        float a = a_red[tid] + a_red[tid + 81] + a_red[tid + 162];
        a_val = valid_k ? a : -INFINITY;
        a_s[tid] = a_val;
    }
    __syncthreads();

    // ---- softmax over 81 (wave-0 butterfly) ----
    if (tid < 64) {
        float m = a_s[tid];
        if (tid + 64 < 81) m = fmaxf(m, a_s[tid + 64]);
        for (int o = 32; o >= 1; o >>= 1) m = fmaxf(m, __shfl_xor(m, o));
        if (tid == 0) m_sh = m;
    }
    __syncthreads();
    {
        float e = 0.f;
        if (tid < 81 && valid_k) e = expf(a_val - m_sh);
        if (tid < 81) e_s[tid] = e;
    }
    __syncthreads();
    if (tid < 64) {
        float sv = e_s[tid] + ((tid + 64 < 81) ? e_s[tid + 64] : 0.f);
        for (int o = 32; o >= 1; o >>= 1) sv += __shfl_xor(sv, o);
        if (tid == 0) inv_sh = 1.f / sv;
    }
    __syncthreads();
    if (tid < 81) {
        int i = (tid * 57) >> 9;
        int j = tid - i * 9;
        float g = expf(rex_s[i] + cex_s[j]);
        w_s[tid] = e_s[tid] * inv_sh * g;
    }
    __syncthreads();

    // ---- pass 2: out[d] = sum_k w_k * win[k][d] (LDS only) ----
    float acc = 0.f;
#pragma unroll
    for (int k = 0; k < 81; k++)
        acc = fmaf(w_s[k], __bfloat162float(win[k][tid]), acc);
    out[(size_t)bt * Dd + tid] = acc;
}

extern "C" void kernel_launch(void* const* d_in, const int* in_sizes, int n_in,
                              void* d_out, int out_size, void* d_ws, size_t ws_size,
                              hipStream_t stream) {
    const float* q   = (const float*)d_in[0];
    const float* c_t = (const float*)d_in[1];
    const float* W_a = (const float*)d_in[2];
    const float* W_p = (const float*)d_in[3];
    const float* V_p = (const float*)d_in[4];
    float* out  = (float*)d_out;
    float* u_ws = (float*)d_ws;                       // 2 MB
    float* p_ws = u_ws + (size_t)NBT * Dd;            // 16 KB
    float* WpT  = p_ws + (size_t)NBT * 2;             // 512 KB

    transpose_wp<<<dim3(16, 8), 256, 0, stream>>>(W_p, WpT);
    prep_kernel<<<NBT / TOK, 512, 0, stream>>>(c_t, W_a, WpT, V_p, u_ws, p_ws);
    attn_kernel<<<NBT, 256, 0, stream>>>(q, u_ws, p_ws, out);
}